// Round 1
// baseline (3352.777 us; speedup 1.0000x reference)
//
#include <hip/hip_runtime.h>
#include <math.h>

// Problem constants
#define NCN 1024
#define NDN 64
#define ECE 16384
#define EDE 1024
#define FCF 128
#define FDF 32
#define HDIM 1024
#define RH 256
#define NG 768   // 3*RH
#define TT 64    // timesteps = ND

// Workspace layout (float offsets). Total ~28.5 MB.
#define OFF_DEG_OC 0
#define OFF_DEG_IC 1024
#define OFF_DEG_OD 2048
#define OFF_DEG_ID 2112
#define OFF_AGG_C  2176
#define SZ_AGG_C   (1024*1025)
#define OFF_X1C    (OFF_AGG_C + SZ_AGG_C)
#define OFF_EMB_C  (OFF_X1C + 1024*1024)
#define OFF_AGG_D  (OFF_EMB_C + 1024*1024)
#define SZ_AGG_D   (64*1025)
#define OFF_X1D    (OFF_AGG_D + SZ_AGG_D)
#define OFF_EMB_D  (OFF_X1D + 64*1024)
#define OFF_AX     (OFF_EMB_D + 64*1024)      // [2][1024][768]
#define OFF_DX     (OFF_AX + 2*1024*768)      // [2][64][768]  (b_in folded in)
#define OFF_H      (OFF_DX + 2*64*768)        // [2048][256]  rows 0..1023 fwd, 1024.. bwd
#define OFF_REC    (OFF_H + 2048*256)         // [2048][768]

#define EPI_NONE 0
#define EPI_BIAS 1
#define EPI_GCONV 2
#define EPI_GCONV_ELU 3

__global__ void fill_k(float* p, int n, float v) {
    int i = blockIdx.x * blockDim.x + threadIdx.x;
    int stride = gridDim.x * blockDim.x;
    for (; i < n; i += stride) p[i] = v;
}

__global__ void degree_k(const int* __restrict__ csrc, const int* __restrict__ cdst,
                         const int* __restrict__ dsrc, const int* __restrict__ ddst,
                         float* ws) {
    int i = blockIdx.x * blockDim.x + threadIdx.x;
    if (i < ECE) {
        atomicAdd(&ws[OFF_DEG_OC + csrc[i]], 1.0f);
        atomicAdd(&ws[OFF_DEG_IC + cdst[i]], 1.0f);
    } else if (i < ECE + EDE) {
        int e = i - ECE;
        atomicAdd(&ws[OFF_DEG_OD + dsrc[e]], 1.0f);
        atomicAdd(&ws[OFF_DEG_ID + ddst[e]], 1.0f);
    }
}

// agg[dst, f] += feat[src, f] * out_deg[src]^-0.5   (feat leading dim == F, F power of 2)
__global__ void agg_k(const float* __restrict__ feat, int F, int logF,
                      const int* __restrict__ src, const int* __restrict__ dst,
                      int E, const float* __restrict__ degout,
                      float* __restrict__ agg, int lda) {
    int i = blockIdx.x * blockDim.x + threadIdx.x;
    int total = E << logF;
    if (i >= total) return;
    int e = i >> logF;
    int f = i & (F - 1);
    int s = src[e];
    float nv = feat[(s << logF) + f] * rsqrtf(fmaxf(degout[s], 1.0f));
    atomicAdd(&agg[dst[e] * lda + f], nv);
}

// write raw in-degree into column F of agg (the concat'd edge-count feature)
__global__ void degcol_k(float* agg, int lda, int F, const float* __restrict__ degin, int n) {
    int i = blockIdx.x * blockDim.x + threadIdx.x;
    if (i < n) agg[i * lda + F] = degin[i];
}

// Generic fp32 tiled GEMM: C[M,N] = A[M,K](lda) * B[K,N](ldb, row-major) + epilogue
// 64x64 tile, BK=16, 256 threads, 4x4 per thread.
__global__ __launch_bounds__(256)
void gemm_k(const float* __restrict__ A, int lda,
            const float* __restrict__ B, int ldb,
            float* __restrict__ C, int ldc,
            int M, int N, int K, int epi,
            const float* __restrict__ scale, const float* __restrict__ bias) {
    __shared__ float As[16][64];
    __shared__ float Bs[16][64];
    int t = threadIdx.x;
    int tx = t & 15, ty = t >> 4;
    int row0 = blockIdx.y * 64, col0 = blockIdx.x * 64;
    float acc[4][4] = {};
    int ktiles = (K + 15) >> 4;
    for (int kt = 0; kt < ktiles; ++kt) {
        int k0 = kt << 4;
#pragma unroll
        for (int l = 0; l < 4; ++l) {
            int idx = t + l * 256;
            int r = idx >> 4, c = idx & 15;
            int gr = row0 + r, gc = k0 + c;
            As[c][r] = (gc < K && gr < M) ? A[gr * lda + gc] : 0.0f;
        }
#pragma unroll
        for (int l = 0; l < 4; ++l) {
            int idx = t + l * 256;
            int r = idx >> 6, c = idx & 63;
            int gk = k0 + r, gc = col0 + c;
            Bs[r][c] = (gk < K && gc < N) ? B[gk * ldb + gc] : 0.0f;
        }
        __syncthreads();
#pragma unroll
        for (int kk = 0; kk < 16; ++kk) {
            float a0 = As[kk][ty * 4 + 0], a1 = As[kk][ty * 4 + 1];
            float a2 = As[kk][ty * 4 + 2], a3 = As[kk][ty * 4 + 3];
            float b0 = Bs[kk][tx * 4 + 0], b1 = Bs[kk][tx * 4 + 1];
            float b2 = Bs[kk][tx * 4 + 2], b3 = Bs[kk][tx * 4 + 3];
            acc[0][0] += a0 * b0; acc[0][1] += a0 * b1; acc[0][2] += a0 * b2; acc[0][3] += a0 * b3;
            acc[1][0] += a1 * b0; acc[1][1] += a1 * b1; acc[1][2] += a1 * b2; acc[1][3] += a1 * b3;
            acc[2][0] += a2 * b0; acc[2][1] += a2 * b1; acc[2][2] += a2 * b2; acc[2][3] += a2 * b3;
            acc[3][0] += a3 * b0; acc[3][1] += a3 * b1; acc[3][2] += a3 * b2; acc[3][3] += a3 * b3;
        }
        __syncthreads();
    }
#pragma unroll
    for (int i = 0; i < 4; ++i) {
#pragma unroll
        for (int j = 0; j < 4; ++j) {
            int r = row0 + ty * 4 + i, c = col0 + tx * 4 + j;
            if (r < M && c < N) {
                float v = acc[i][j];
                if (epi == EPI_BIAS) v += bias[c];
                else if (epi >= EPI_GCONV) {
                    v = v * rsqrtf(fmaxf(scale[r], 1.0f)) + bias[c];
                    if (epi == EPI_GCONV_ELU) v = (v > 0.0f) ? v : expm1f(v);
                }
                C[r * ldc + c] = v;
            }
        }
    }
}

// GRU step recurrent GEMM: rec[2048,768] = h[2048,256] @ Wh_{f|b}[256,768] + b_rec
// rows 0..1023 use forward weights, 1024..2047 backward.
__global__ __launch_bounds__(256)
void step_gemm_k(const float* __restrict__ hbuf,
                 const float* __restrict__ Whf, const float* __restrict__ Whb,
                 const float* __restrict__ brf, const float* __restrict__ brb,
                 float* __restrict__ rec) {
    __shared__ float As[16][64];
    __shared__ float Bs[16][64];
    int t = threadIdx.x;
    int tx = t & 15, ty = t >> 4;
    int br = blockIdx.y, bc = blockIdx.x;
    const float* B = (br < 16) ? Whf : Whb;
    const float* bias = (br < 16) ? brf : brb;
    int row0 = br * 64, col0 = bc * 64;
    float acc[4][4] = {};
    for (int kt = 0; kt < 16; ++kt) {
        int k0 = kt << 4;
#pragma unroll
        for (int l = 0; l < 4; ++l) {
            int idx = t + l * 256;
            int r = idx >> 4, c = idx & 15;
            As[c][r] = hbuf[(row0 + r) * 256 + k0 + c];
        }
#pragma unroll
        for (int l = 0; l < 4; ++l) {
            int idx = t + l * 256;
            int r = idx >> 6, c = idx & 63;
            Bs[r][c] = B[(k0 + r) * 768 + col0 + c];
        }
        __syncthreads();
#pragma unroll
        for (int kk = 0; kk < 16; ++kk) {
            float a0 = As[kk][ty * 4 + 0], a1 = As[kk][ty * 4 + 1];
            float a2 = As[kk][ty * 4 + 2], a3 = As[kk][ty * 4 + 3];
            float b0 = Bs[kk][tx * 4 + 0], b1 = Bs[kk][tx * 4 + 1];
            float b2 = Bs[kk][tx * 4 + 2], b3 = Bs[kk][tx * 4 + 3];
            acc[0][0] += a0 * b0; acc[0][1] += a0 * b1; acc[0][2] += a0 * b2; acc[0][3] += a0 * b3;
            acc[1][0] += a1 * b0; acc[1][1] += a1 * b1; acc[1][2] += a1 * b2; acc[1][3] += a1 * b3;
            acc[2][0] += a2 * b0; acc[2][1] += a2 * b1; acc[2][2] += a2 * b2; acc[2][3] += a2 * b3;
            acc[3][0] += a3 * b0; acc[3][1] += a3 * b1; acc[3][2] += a3 * b2; acc[3][3] += a3 * b3;
        }
        __syncthreads();
    }
#pragma unroll
    for (int i = 0; i < 4; ++i)
#pragma unroll
        for (int j = 0; j < 4; ++j) {
            int r = row0 + ty * 4 + i, c = col0 + tx * 4 + j;
            rec[r * 768 + c] = acc[i][j] + bias[c];
        }
}

// Gate update + incremental head accumulation.
// block = one row (b, dir); 256 threads = hidden dim j.
__global__ __launch_bounds__(256)
void gru_gate_k(float* ws, const float* __restrict__ Wf, float* __restrict__ out, int s) {
    int row = blockIdx.x;          // 0..2047
    int dir = row >> 10;
    int b = row & 1023;
    int t = dir ? (63 - s) : s;
    int j = threadIdx.x;
    const float* AX = ws + OFF_AX + (size_t)dir * 1024 * 768 + b * 768;
    const float* DX = ws + OFF_DX + (size_t)dir * 64 * 768 + t * 768;
    const float* rec = ws + OFF_REC + (size_t)row * 768;
    float xz = AX[j] + DX[j];
    float xr = AX[j + 256] + DX[j + 256];
    float xh = AX[j + 512] + DX[j + 512];
    float rz = rec[j], rr = rec[j + 256], rh = rec[j + 512];
    float z = 1.0f / (1.0f + expf(-(xz + rz)));
    float r = 1.0f / (1.0f + expf(-(xr + rr)));
    float hh = tanhf(xh + r * rh);
    float* hp = ws + OFF_H + (size_t)row * 256 + j;
    float hold = *hp;
    float hn = z * hold + (1.0f - z) * hh;
    *hp = hn;
    // partial logits y[b,t] @ Wf (this direction's 256-row slice of Wf)
    int wr = dir * 256 + j;
    float p0 = hn * Wf[wr * 3 + 0];
    float p1 = hn * Wf[wr * 3 + 1];
    float p2 = hn * Wf[wr * 3 + 2];
#pragma unroll
    for (int off = 32; off; off >>= 1) {
        p0 += __shfl_down(p0, off);
        p1 += __shfl_down(p1, off);
        p2 += __shfl_down(p2, off);
    }
    __shared__ float sm[4][3];
    int wid = j >> 6;
    if ((j & 63) == 0) { sm[wid][0] = p0; sm[wid][1] = p1; sm[wid][2] = p2; }
    __syncthreads();
    if (j == 0) {
        float q0 = sm[0][0] + sm[1][0] + sm[2][0] + sm[3][0];
        float q1 = sm[0][1] + sm[1][1] + sm[2][1] + sm[3][1];
        float q2 = sm[0][2] + sm[1][2] + sm[2][2] + sm[3][2];
        float* o = out + ((size_t)b * 64 + t) * 3;
        o[0] += q0; o[1] += q1; o[2] += q2;   // fwd/bwd write distinct t per launch
    }
}

__global__ void initout_k(float* out, const float* __restrict__ bf) {
    int i = blockIdx.x * blockDim.x + threadIdx.x;
    if (i < NCN * TT) {
        out[3 * i + 0] = bf[0];
        out[3 * i + 1] = bf[1];
        out[3 * i + 2] = bf[2];
    }
}

__global__ void lsm_k(float* out) {
    int i = blockIdx.x * blockDim.x + threadIdx.x;
    if (i >= NCN * TT) return;
    float v0 = out[3 * i], v1 = out[3 * i + 1], v2 = out[3 * i + 2];
    float m = fmaxf(v0, fmaxf(v1, v2));
    float l = m + logf(expf(v0 - m) + expf(v1 - m) + expf(v2 - m));
    out[3 * i] = v0 - l; out[3 * i + 1] = v1 - l; out[3 * i + 2] = v2 - l;
}

extern "C" void kernel_launch(void* const* d_in, const int* in_sizes, int n_in,
                              void* d_out, int out_size, void* d_ws, size_t ws_size,
                              hipStream_t stream) {
    const float* comp_feat = (const float*)d_in[0];
    const float* dev_feat  = (const float*)d_in[1];
    const int* comp_src = (const int*)d_in[2];
    const int* comp_dst = (const int*)d_in[3];
    const int* dev_src  = (const int*)d_in[4];
    const int* dev_dst  = (const int*)d_in[5];
    const float* W1c = (const float*)d_in[6];  const float* b1c = (const float*)d_in[7];
    const float* W2c = (const float*)d_in[8];  const float* b2c = (const float*)d_in[9];
    const float* W1d = (const float*)d_in[10]; const float* b1d = (const float*)d_in[11];
    const float* W2d = (const float*)d_in[12]; const float* b2d = (const float*)d_in[13];
    const float* Wx_f = (const float*)d_in[14]; const float* Wh_f = (const float*)d_in[15];
    const float* b_f  = (const float*)d_in[16];
    const float* Wx_b = (const float*)d_in[17]; const float* Wh_b = (const float*)d_in[18];
    const float* b_b  = (const float*)d_in[19];
    const float* Wf = (const float*)d_in[20];  const float* bf = (const float*)d_in[21];
    float* out = (float*)d_out;
    float* ws = (float*)d_ws;

    // zero accumulators
    fill_k<<<16, 256, 0, stream>>>(ws, 2176, 0.0f);
    fill_k<<<4096, 256, 0, stream>>>(ws + OFF_AGG_C, SZ_AGG_C, 0.0f);
    fill_k<<<256, 256, 0, stream>>>(ws + OFF_AGG_D, SZ_AGG_D, 0.0f);

    degree_k<<<(ECE + EDE + 255) / 256, 256, 0, stream>>>(comp_src, comp_dst, dev_src, dev_dst, ws);

    // ---- GCN layer 1 ----
    agg_k<<<(ECE * FCF + 255) / 256, 256, 0, stream>>>(comp_feat, FCF, 7, comp_src, comp_dst, ECE,
                                                       ws + OFF_DEG_OC, ws + OFF_AGG_C, FCF + 1);
    agg_k<<<(EDE * FDF + 255) / 256, 256, 0, stream>>>(dev_feat, FDF, 5, dev_src, dev_dst, EDE,
                                                       ws + OFF_DEG_OD, ws + OFF_AGG_D, FDF + 1);
    degcol_k<<<4, 256, 0, stream>>>(ws + OFF_AGG_C, FCF + 1, FCF, ws + OFF_DEG_IC, NCN);
    degcol_k<<<1, 64, 0, stream>>>(ws + OFF_AGG_D, FDF + 1, FDF, ws + OFF_DEG_ID, NDN);

    gemm_k<<<dim3(16, 16), 256, 0, stream>>>(ws + OFF_AGG_C, FCF + 1, W1c, HDIM,
                                             ws + OFF_X1C, HDIM, NCN, HDIM, FCF + 1,
                                             EPI_GCONV_ELU, ws + OFF_DEG_IC, b1c);
    gemm_k<<<dim3(16, 1), 256, 0, stream>>>(ws + OFF_AGG_D, FDF + 1, W1d, HDIM,
                                            ws + OFF_X1D, HDIM, NDN, HDIM, FDF + 1,
                                            EPI_GCONV_ELU, ws + OFF_DEG_ID, b1d);

    // ---- GCN layer 2 ----
    fill_k<<<4096, 256, 0, stream>>>(ws + OFF_AGG_C, SZ_AGG_C, 0.0f);
    fill_k<<<256, 256, 0, stream>>>(ws + OFF_AGG_D, SZ_AGG_D, 0.0f);
    agg_k<<<(ECE * HDIM + 255) / 256, 256, 0, stream>>>(ws + OFF_X1C, HDIM, 10, comp_src, comp_dst, ECE,
                                                        ws + OFF_DEG_OC, ws + OFF_AGG_C, HDIM + 1);
    agg_k<<<(EDE * HDIM + 255) / 256, 256, 0, stream>>>(ws + OFF_X1D, HDIM, 10, dev_src, dev_dst, EDE,
                                                        ws + OFF_DEG_OD, ws + OFF_AGG_D, HDIM + 1);
    degcol_k<<<4, 256, 0, stream>>>(ws + OFF_AGG_C, HDIM + 1, HDIM, ws + OFF_DEG_IC, NCN);
    degcol_k<<<1, 64, 0, stream>>>(ws + OFF_AGG_D, HDIM + 1, HDIM, ws + OFF_DEG_ID, NDN);

    gemm_k<<<dim3(16, 16), 256, 0, stream>>>(ws + OFF_AGG_C, HDIM + 1, W2c, HDIM,
                                             ws + OFF_EMB_C, HDIM, NCN, HDIM, HDIM + 1,
                                             EPI_GCONV, ws + OFF_DEG_IC, b2c);
    gemm_k<<<dim3(16, 1), 256, 0, stream>>>(ws + OFF_AGG_D, HDIM + 1, W2d, HDIM,
                                            ws + OFF_EMB_D, HDIM, NDN, HDIM, HDIM + 1,
                                            EPI_GCONV, ws + OFF_DEG_ID, b2d);

    // ---- GRU input projections: xp[b,t] = Ax[dir][b] + Dx[dir][t]  (b_in folded into Dx) ----
    gemm_k<<<dim3(12, 16), 256, 0, stream>>>(ws + OFF_EMB_C, HDIM, Wx_f, NG,
                                             ws + OFF_AX, NG, NCN, NG, HDIM,
                                             EPI_NONE, nullptr, nullptr);
    gemm_k<<<dim3(12, 16), 256, 0, stream>>>(ws + OFF_EMB_C, HDIM, Wx_b, NG,
                                             ws + OFF_AX + 1024 * 768, NG, NCN, NG, HDIM,
                                             EPI_NONE, nullptr, nullptr);
    gemm_k<<<dim3(12, 1), 256, 0, stream>>>(ws + OFF_EMB_D, HDIM, Wx_f + 1024 * 768, NG,
                                            ws + OFF_DX, NG, NDN, NG, HDIM,
                                            EPI_BIAS, nullptr, b_f);
    gemm_k<<<dim3(12, 1), 256, 0, stream>>>(ws + OFF_EMB_D, HDIM, Wx_b + 1024 * 768, NG,
                                            ws + OFF_DX + 64 * 768, NG, NDN, NG, HDIM,
                                            EPI_BIAS, nullptr, b_b);

    // ---- GRU scan ----
    fill_k<<<2048, 256, 0, stream>>>(ws + OFF_H, 2048 * 256, 0.0f);
    initout_k<<<256, 256, 0, stream>>>(out, bf);
    for (int s = 0; s < TT; ++s) {
        step_gemm_k<<<dim3(12, 32), 256, 0, stream>>>(ws + OFF_H, Wh_f, Wh_b,
                                                      b_f + 768, b_b + 768, ws + OFF_REC);
        gru_gate_k<<<2048, 256, 0, stream>>>(ws, Wf, out, s);
    }
    lsm_k<<<256, 256, 0, stream>>>(out);
}

// Round 8
// 2014.261 us; speedup vs baseline: 1.6645x; 1.6645x over previous
//
#include <hip/hip_runtime.h>
#include <math.h>

// Problem constants
#define NCN 1024
#define NDN 64
#define ECE 16384
#define EDE 1024
#define FCF 128
#define FDF 32
#define HDIM 1024
#define RH 256
#define NG 768   // 3*RH
#define TT 64    // timesteps = ND

// Workspace layout (float offsets). Leading dims padded to %4 for float4 staging.
#define OFF_DEG_OC 0
#define OFF_DEG_IC 1024
#define OFF_DEG_OD 2048
#define OFF_DEG_ID 2112
#define OFF_AGG_C  2176
#define SZ_AGG_C   (1024*1028)
#define OFF_X1C    (OFF_AGG_C + SZ_AGG_C)
#define OFF_EMB_C  (OFF_X1C + 1024*1024)
#define OFF_AGG_D  (OFF_EMB_C + 1024*1024)
#define SZ_AGG_D   (64*1028)
#define OFF_X1D    (OFF_AGG_D + SZ_AGG_D)
#define OFF_EMB_D  (OFF_X1D + 64*1024)
#define OFF_AX     (OFF_EMB_D + 64*1024)      // [2][1024][768]
#define OFF_DX     (OFF_AX + 2*1024*768)      // [2][64][768]  (b_in folded in)

#define EPI_NONE 0
#define EPI_BIAS 1
#define EPI_GCONV 2
#define EPI_GCONV_ELU 3

__global__ void fill_k(float* p, int n, float v) {
    int i = blockIdx.x * blockDim.x + threadIdx.x;
    int stride = gridDim.x * blockDim.x;
    for (; i < n; i += stride) p[i] = v;
}

__global__ void degree_k(const int* __restrict__ csrc, const int* __restrict__ cdst,
                         const int* __restrict__ dsrc, const int* __restrict__ ddst,
                         float* ws) {
    int i = blockIdx.x * blockDim.x + threadIdx.x;
    if (i < ECE) {
        atomicAdd(&ws[OFF_DEG_OC + csrc[i]], 1.0f);
        atomicAdd(&ws[OFF_DEG_IC + cdst[i]], 1.0f);
    } else if (i < ECE + EDE) {
        int e = i - ECE;
        atomicAdd(&ws[OFF_DEG_OD + dsrc[e]], 1.0f);
        atomicAdd(&ws[OFF_DEG_ID + ddst[e]], 1.0f);
    }
}

// agg[dst, f] += feat[src, f] * out_deg[src]^-0.5   (feat leading dim == F, F power of 2)
__global__ void agg_k(const float* __restrict__ feat, int F, int logF,
                      const int* __restrict__ src, const int* __restrict__ dst,
                      int E, const float* __restrict__ degout,
                      float* __restrict__ agg, int lda) {
    int i = blockIdx.x * blockDim.x + threadIdx.x;
    int total = E << logF;
    if (i >= total) return;
    int e = i >> logF;
    int f = i & (F - 1);
    int s = src[e];
    float nv = feat[(s << logF) + f] * rsqrtf(fmaxf(degout[s], 1.0f));
    atomicAdd(&agg[dst[e] * lda + f], nv);
}

// write raw in-degree into column F of agg (the concat'd edge-count feature)
__global__ void degcol_k(float* agg, int lda, int F, const float* __restrict__ degin, int n) {
    int i = blockIdx.x * blockDim.x + threadIdx.x;
    if (i < n) agg[i * lda + F] = degin[i];
}

// Generic fp32 tiled GEMM: C[M,N] = A[M,K](lda) * B[K,N](ldb, row-major) + epilogue
// 64x64 tile, BK=16, 256 threads, 4x4 per thread. As padded to stride 68:
// write addr = c*68+r -> lanes consecutive r -> conflict-free (was 16-way at 64).
__global__ __launch_bounds__(256)
void gemm_k(const float* __restrict__ A, int lda,
            const float* __restrict__ B, int ldb,
            float* __restrict__ C, int ldc,
            int M, int N, int K, int epi,
            const float* __restrict__ scale, const float* __restrict__ bias) {
    __shared__ float As[16][68];
    __shared__ float Bs[16][64];
    int t = threadIdx.x;
    int tx = t & 15, ty = t >> 4;
    int row0 = blockIdx.y * 64, col0 = blockIdx.x * 64;
    int ar = t & 63, ac4 = t >> 6;        // A staging: row ar, k-cols ac4*4..+3
    int bk = t >> 4, bc4 = t & 15;        // B staging: k-row bk, cols bc4*4..+3
    float acc[4][4] = {};
    int ktiles = (K + 15) >> 4;
    bool avec = ((lda & 3) == 0);
    for (int kt = 0; kt < ktiles; ++kt) {
        int k0 = kt << 4;
        bool full = (k0 + 16 <= K);
        // stage A (rows always in-bounds: grid.y*64 == M for all our shapes)
        if (full && avec) {
            float4 av = *(const float4*)(A + (size_t)(row0 + ar) * lda + k0 + ac4 * 4);
            As[ac4 * 4 + 0][ar] = av.x; As[ac4 * 4 + 1][ar] = av.y;
            As[ac4 * 4 + 2][ar] = av.z; As[ac4 * 4 + 3][ar] = av.w;
        } else {
#pragma unroll
            for (int j = 0; j < 4; ++j) {
                int kc = k0 + ac4 * 4 + j;
                As[ac4 * 4 + j][ar] = (kc < K) ? A[(size_t)(row0 + ar) * lda + kc] : 0.0f;
            }
        }
        // stage B (cols always in-bounds: N multiple of 64)
        if (full) {
            float4 bv = *(const float4*)(B + (size_t)(k0 + bk) * ldb + col0 + bc4 * 4);
            *(float4*)&Bs[bk][bc4 * 4] = bv;
        } else {
            int kr = k0 + bk;
#pragma unroll
            for (int j = 0; j < 4; ++j)
                Bs[bk][bc4 * 4 + j] = (kr < K) ? B[(size_t)kr * ldb + col0 + bc4 * 4 + j] : 0.0f;
        }
        __syncthreads();
#pragma unroll
        for (int kk = 0; kk < 16; ++kk) {
            float4 a = *(const float4*)&As[kk][ty * 4];
            float4 b = *(const float4*)&Bs[kk][tx * 4];
            acc[0][0] += a.x * b.x; acc[0][1] += a.x * b.y; acc[0][2] += a.x * b.z; acc[0][3] += a.x * b.w;
            acc[1][0] += a.y * b.x; acc[1][1] += a.y * b.y; acc[1][2] += a.y * b.z; acc[1][3] += a.y * b.w;
            acc[2][0] += a.z * b.x; acc[2][1] += a.z * b.y; acc[2][2] += a.z * b.z; acc[2][3] += a.z * b.w;
            acc[3][0] += a.w * b.x; acc[3][1] += a.w * b.y; acc[3][2] += a.w * b.z; acc[3][3] += a.w * b.w;
        }
        __syncthreads();
    }
#pragma unroll
    for (int i = 0; i < 4; ++i) {
#pragma unroll
        for (int j = 0; j < 4; ++j) {
            int r = row0 + ty * 4 + i, c = col0 + tx * 4 + j;
            if (r < M && c < N) {
                float v = acc[i][j];
                if (epi == EPI_BIAS) v += bias[c];
                else if (epi >= EPI_GCONV) {
                    v = v * rsqrtf(fmaxf(scale[r], 1.0f)) + bias[c];
                    if (epi == EPI_GCONV_ELU) v = (v > 0.0f) ? v : expm1f(v);
                }
                C[(size_t)r * ldc + c] = v;
            }
        }
    }
}

// ---------------------------------------------------------------------------
// Persistent bidirectional GRU scan. The recurrence is row-independent
// (h[b,dir] couples only to itself), so no cross-WG sync is needed at all.
// 256 WGs x 512 threads. WG = (dir = wg>>7, rg = wg&127) owns 8 batch rows.
// Thread = (c = tid&255 hidden dim, rh = tid>>8 row-quad). Each thread owns
// all 3 gate columns {c, c+256, c+512} for its 4 rows -> gate math fully
// register-local. h[8][256] in LDS; Wh streamed from L2 (row-coalesced,
// rh-halves dedup in L1); AX/b_rec/Wf preloaded to registers (step-invariant).
// Head y@Wf accumulated incrementally via wave-reduce + atomicAdd.
// ---------------------------------------------------------------------------
__global__ __launch_bounds__(512, 1)
void scan_k(const float* __restrict__ AX, const float* __restrict__ DX,
            const float* __restrict__ Whf, const float* __restrict__ Whb,
            const float* __restrict__ b_f, const float* __restrict__ b_b,
            const float* __restrict__ Wf, float* __restrict__ out) {
    __shared__ float sH[8][260];   // stride 260: 16B-aligned rows for float4 broadcast reads
    int wg = blockIdx.x;
    int dir = wg >> 7;
    int rg = wg & 127;
    int tid = threadIdx.x;
    int c = tid & 255;
    int rh = tid >> 8;             // 0/1 -> rows rh*4 .. rh*4+3
    const float* Wh = dir ? Whb : Whf;               // [256][768]
    const float* brec = (dir ? b_b : b_f) + 768;     // recurrent bias row
    const float* dxb = DX + (size_t)dir * 64 * 768;

    // step-invariant register preloads
    float ax[4][3];
#pragma unroll
    for (int rr = 0; rr < 4; ++rr) {
        const float* arow = AX + ((size_t)dir * 1024 + rg * 8 + rh * 4 + rr) * 768;
#pragma unroll
        for (int g = 0; g < 3; ++g) ax[rr][g] = arow[g * 256 + c];
    }
    float br[3];
#pragma unroll
    for (int g = 0; g < 3; ++g) br[g] = brec[g * 256 + c];
    float wf[3];
#pragma unroll
    for (int j = 0; j < 3; ++j) wf[j] = Wf[(dir * 256 + c) * 3 + j];

#pragma unroll
    for (int rr = 0; rr < 4; ++rr) sH[rh * 4 + rr][c] = 0.0f;
    __syncthreads();

    for (int s = 0; s < 64; ++s) {
        int t = dir ? (63 - s) : s;
        // ---- rec = h @ Wh (bias added in gate) ----
        float acc[4][3];
#pragma unroll
        for (int rr = 0; rr < 4; ++rr)
#pragma unroll
            for (int g = 0; g < 3; ++g) acc[rr][g] = 0.0f;

        const float* wp = Wh + c;
#pragma unroll 2
        for (int k4 = 0; k4 < 64; ++k4) {
            float4 h4[4];
#pragma unroll
            for (int rr = 0; rr < 4; ++rr)
                h4[rr] = *(const float4*)&sH[rh * 4 + rr][k4 * 4];
#pragma unroll
            for (int kk = 0; kk < 4; ++kk) {
                const float* wk = wp + (size_t)(k4 * 4 + kk) * 768;
                float w0 = wk[0], w1 = wk[256], w2 = wk[512];
#pragma unroll
                for (int rr = 0; rr < 4; ++rr) {
                    float hv = (kk == 0) ? h4[rr].x : (kk == 1) ? h4[rr].y
                             : (kk == 2) ? h4[rr].z : h4[rr].w;
                    acc[rr][0] += hv * w0;
                    acc[rr][1] += hv * w1;
                    acc[rr][2] += hv * w2;
                }
            }
        }
        __syncthreads();   // all rec reads of sH complete before gate writes

        // ---- gate + head partial (all register-local per thread) ----
        const float* dxr = dxb + (size_t)t * 768;
        float dx0 = dxr[c], dx1 = dxr[256 + c], dx2 = dxr[512 + c];
        float p[4][3];
#pragma unroll
        for (int rr = 0; rr < 4; ++rr) {
            int r = rh * 4 + rr;
            float hold = sH[r][c];
            float z  = 1.0f / (1.0f + expf(-(ax[rr][0] + dx0 + acc[rr][0] + br[0])));
            float rg_ = 1.0f / (1.0f + expf(-(ax[rr][1] + dx1 + acc[rr][1] + br[1])));
            float hh = tanhf(ax[rr][2] + dx2 + rg_ * (acc[rr][2] + br[2]));
            float hn = z * hold + (1.0f - z) * hh;
            sH[r][c] = hn;
            p[rr][0] = hn * wf[0]; p[rr][1] = hn * wf[1]; p[rr][2] = hn * wf[2];
        }
        // wave-reduce the 12 head partials, lane0 accumulates to out
#pragma unroll
        for (int off = 32; off; off >>= 1)
#pragma unroll
            for (int rr = 0; rr < 4; ++rr)
#pragma unroll
                for (int j = 0; j < 3; ++j)
                    p[rr][j] += __shfl_down(p[rr][j], off);
        if ((tid & 63) == 0) {
#pragma unroll
            for (int rr = 0; rr < 4; ++rr) {
                int b = rg * 8 + rh * 4 + rr;
                float* o = out + ((size_t)b * 64 + t) * 3;
                atomicAdd(&o[0], p[rr][0]);
                atomicAdd(&o[1], p[rr][1]);
                atomicAdd(&o[2], p[rr][2]);
            }
        }
        __syncthreads();   // gate writes visible before next step's rec reads
    }
}

__global__ void initout_k(float* out, const float* __restrict__ bf) {
    int i = blockIdx.x * blockDim.x + threadIdx.x;
    if (i < NCN * TT) {
        out[3 * i + 0] = bf[0];
        out[3 * i + 1] = bf[1];
        out[3 * i + 2] = bf[2];
    }
}

__global__ void lsm_k(float* out) {
    int i = blockIdx.x * blockDim.x + threadIdx.x;
    if (i >= NCN * TT) return;
    float v0 = out[3 * i], v1 = out[3 * i + 1], v2 = out[3 * i + 2];
    float m = fmaxf(v0, fmaxf(v1, v2));
    float l = m + logf(expf(v0 - m) + expf(v1 - m) + expf(v2 - m));
    out[3 * i] = v0 - l; out[3 * i + 1] = v1 - l; out[3 * i + 2] = v2 - l;
}

extern "C" void kernel_launch(void* const* d_in, const int* in_sizes, int n_in,
                              void* d_out, int out_size, void* d_ws, size_t ws_size,
                              hipStream_t stream) {
    const float* comp_feat = (const float*)d_in[0];
    const float* dev_feat  = (const float*)d_in[1];
    const int* comp_src = (const int*)d_in[2];
    const int* comp_dst = (const int*)d_in[3];
    const int* dev_src  = (const int*)d_in[4];
    const int* dev_dst  = (const int*)d_in[5];
    const float* W1c = (const float*)d_in[6];  const float* b1c = (const float*)d_in[7];
    const float* W2c = (const float*)d_in[8];  const float* b2c = (const float*)d_in[9];
    const float* W1d = (const float*)d_in[10]; const float* b1d = (const float*)d_in[11];
    const float* W2d = (const float*)d_in[12]; const float* b2d = (const float*)d_in[13];
    const float* Wx_f = (const float*)d_in[14]; const float* Wh_f = (const float*)d_in[15];
    const float* b_f  = (const float*)d_in[16];
    const float* Wx_b = (const float*)d_in[17]; const float* Wh_b = (const float*)d_in[18];
    const float* b_b  = (const float*)d_in[19];
    const float* Wf = (const float*)d_in[20];  const float* bf = (const float*)d_in[21];
    float* out = (float*)d_out;
    float* ws = (float*)d_ws;

    // zero degree + agg accumulators
    fill_k<<<16, 256, 0, stream>>>(ws, 2176, 0.0f);
    fill_k<<<4096, 256, 0, stream>>>(ws + OFF_AGG_C, SZ_AGG_C, 0.0f);
    fill_k<<<256, 256, 0, stream>>>(ws + OFF_AGG_D, SZ_AGG_D, 0.0f);

    degree_k<<<(ECE + EDE + 255) / 256, 256, 0, stream>>>(comp_src, comp_dst, dev_src, dev_dst, ws);

    // ---- GCN layer 1 ----  (agg lda padded: 128+1->132, 32+1->36)
    agg_k<<<(ECE * FCF + 255) / 256, 256, 0, stream>>>(comp_feat, FCF, 7, comp_src, comp_dst, ECE,
                                                       ws + OFF_DEG_OC, ws + OFF_AGG_C, 132);
    agg_k<<<(EDE * FDF + 255) / 256, 256, 0, stream>>>(dev_feat, FDF, 5, dev_src, dev_dst, EDE,
                                                       ws + OFF_DEG_OD, ws + OFF_AGG_D, 36);
    degcol_k<<<4, 256, 0, stream>>>(ws + OFF_AGG_C, 132, FCF, ws + OFF_DEG_IC, NCN);
    degcol_k<<<1, 64, 0, stream>>>(ws + OFF_AGG_D, 36, FDF, ws + OFF_DEG_ID, NDN);

    gemm_k<<<dim3(16, 16), 256, 0, stream>>>(ws + OFF_AGG_C, 132, W1c, HDIM,
                                             ws + OFF_X1C, HDIM, NCN, HDIM, FCF + 1,
                                             EPI_GCONV_ELU, ws + OFF_DEG_IC, b1c);
    gemm_k<<<dim3(16, 1), 256, 0, stream>>>(ws + OFF_AGG_D, 36, W1d, HDIM,
                                            ws + OFF_X1D, HDIM, NDN, HDIM, FDF + 1,
                                            EPI_GCONV_ELU, ws + OFF_DEG_ID, b1d);

    // ---- GCN layer 2 ----  (agg lda 1024+1 -> 1028)
    fill_k<<<4096, 256, 0, stream>>>(ws + OFF_AGG_C, SZ_AGG_C, 0.0f);
    fill_k<<<256, 256, 0, stream>>>(ws + OFF_AGG_D, SZ_AGG_D, 0.0f);
    agg_k<<<(ECE * HDIM + 255) / 256, 256, 0, stream>>>(ws + OFF_X1C, HDIM, 10, comp_src, comp_dst, ECE,
                                                        ws + OFF_DEG_OC, ws + OFF_AGG_C, 1028);
    agg_k<<<(EDE * HDIM + 255) / 256, 256, 0, stream>>>(ws + OFF_X1D, HDIM, 10, dev_src, dev_dst, EDE,
                                                        ws + OFF_DEG_OD, ws + OFF_AGG_D, 1028);
    degcol_k<<<4, 256, 0, stream>>>(ws + OFF_AGG_C, 1028, HDIM, ws + OFF_DEG_IC, NCN);
    degcol_k<<<1, 64, 0, stream>>>(ws + OFF_AGG_D, 1028, HDIM, ws + OFF_DEG_ID, NDN);

    gemm_k<<<dim3(16, 16), 256, 0, stream>>>(ws + OFF_AGG_C, 1028, W2c, HDIM,
                                             ws + OFF_EMB_C, HDIM, NCN, HDIM, HDIM + 1,
                                             EPI_GCONV, ws + OFF_DEG_IC, b2c);
    gemm_k<<<dim3(16, 1), 256, 0, stream>>>(ws + OFF_AGG_D, 1028, W2d, HDIM,
                                            ws + OFF_EMB_D, HDIM, NDN, HDIM, HDIM + 1,
                                            EPI_GCONV, ws + OFF_DEG_ID, b2d);

    // ---- GRU input projections: xp[b,t] = Ax[dir][b] + Dx[dir][t]  (b_in folded into Dx) ----
    gemm_k<<<dim3(12, 16), 256, 0, stream>>>(ws + OFF_EMB_C, HDIM, Wx_f, NG,
                                             ws + OFF_AX, NG, NCN, NG, HDIM,
                                             EPI_NONE, nullptr, nullptr);
    gemm_k<<<dim3(12, 16), 256, 0, stream>>>(ws + OFF_EMB_C, HDIM, Wx_b, NG,
                                             ws + OFF_AX + 1024 * 768, NG, NCN, NG, HDIM,
                                             EPI_NONE, nullptr, nullptr);
    gemm_k<<<dim3(12, 1), 256, 0, stream>>>(ws + OFF_EMB_D, HDIM, Wx_f + 1024 * 768, NG,
                                            ws + OFF_DX, NG, NDN, NG, HDIM,
                                            EPI_BIAS, nullptr, b_f);
    gemm_k<<<dim3(12, 1), 256, 0, stream>>>(ws + OFF_EMB_D, HDIM, Wx_b + 1024 * 768, NG,
                                            ws + OFF_DX + 64 * 768, NG, NDN, NG, HDIM,
                                            EPI_BIAS, nullptr, b_b);

    // ---- persistent GRU scan (single launch, no grid sync needed) ----
    initout_k<<<256, 256, 0, stream>>>(out, bf);
    scan_k<<<256, 512, 0, stream>>>(ws + OFF_AX, ws + OFF_DX, Wh_f, Wh_b,
                                    b_f, b_b, Wf, out);
    lsm_k<<<256, 256, 0, stream>>>(out);
}